// Round 1
// baseline (274.179 us; speedup 1.0000x reference)
//
#include <hip/hip_runtime.h>
#include <math.h>

// Problem constants
#define BATCH 8
#define CHN   64
#define NPTS  8192
#define NH    4
#define HD    64
#define P2    192            // 192 = CHN*3 combined (channel, xyz) index
#define KSPLIT 16
#define KCH   (NPTS / KSPLIT)   // 512 points per k-chunk
#define KT    16                // K-tile staged in LDS

// Workspace layout (float offsets)
#define SZ_GPART (KSPLIT * BATCH * P2 * P2)          // 4,718,592 fl
#define OFF_G    (SZ_GPART)
#define SZ_G     (BATCH * P2 * P2)                   // 294,912 fl
#define OFF_M    (OFF_G + SZ_G)                      // [NH][64][64]
#define OFF_P    (OFF_M + NH * CHN * CHN)            // [NH][64][64]
#define OFF_W    (OFF_P + NH * CHN * CHN)            // [B][NH][12] (9 used)
#define OFF_AT   (OFF_W + BATCH * NH * 12)           // [B][q2=192][p2=192] (Abig transposed, I folded)
// total ≈ 5.34M floats ≈ 21.4 MB

// ---------------------------------------------------------------------------
// Kernel 1: per-batch Gram partials  Gpart[k][b][p][q] = sum_{n in chunk k} F2[p,n]*F2[q,n]
// F2[b][(c*3+t)][n] = feat[b][c][n][t]
// Block: 256 thr, computes a 96x96 tile (pi,qi in {0,1}) for one (b, k-chunk).
// ---------------------------------------------------------------------------
__global__ __launch_bounds__(256) void k_gram(const float* __restrict__ feat,
                                              float* __restrict__ ws) {
    const int bid  = blockIdx.x;
    const int k    = bid & (KSPLIT - 1);
    const int tile = (bid >> 4) & 3;
    const int b    = bid >> 6;
    const int pi   = tile >> 1, qi = tile & 1;
    const int n0   = k * KCH;

    __shared__ float Ap[KT][96];
    __shared__ float Bp[KT][96];

    const int tid = threadIdx.x;
    const int ty = tid >> 4, tx = tid & 15;

    float acc[6][6];
#pragma unroll
    for (int i = 0; i < 6; i++)
#pragma unroll
        for (int j = 0; j < 6; j++) acc[i][j] = 0.0f;

    const float* fb = feat + (size_t)b * CHN * NPTS * 3;

    for (int ks = 0; ks < KCH; ks += KT) {
        // stage 2 panels x (KT x 32 channels x float3) = 1024 float3 loads / 256 thr
#pragma unroll
        for (int e = 0; e < 4; e++) {
            int idx   = e * 256 + tid;
            int panel = idx >> 9;        // 0 = A, 1 = B
            int id    = idx & 511;
            int kk    = id >> 5;
            int ci    = id & 31;
            int cg    = (panel ? qi : pi) * 32 + ci;
            const float* src = fb + ((size_t)cg * NPTS + (size_t)(n0 + ks + kk)) * 3;
            float v0 = src[0], v1 = src[1], v2 = src[2];
            float* dst = panel ? &Bp[kk][ci * 3] : &Ap[kk][ci * 3];
            dst[0] = v0; dst[1] = v1; dst[2] = v2;
        }
        __syncthreads();
#pragma unroll 4
        for (int kk = 0; kk < KT; kk++) {
            float a[6], bb[6];
#pragma unroll
            for (int i = 0; i < 6; i++) a[i] = Ap[kk][ty * 6 + i];
#pragma unroll
            for (int j = 0; j < 6; j++) bb[j] = Bp[kk][tx * 6 + j];
#pragma unroll
            for (int i = 0; i < 6; i++)
#pragma unroll
                for (int j = 0; j < 6; j++)
                    acc[i][j] = fmaf(a[i], bb[j], acc[i][j]);
        }
        __syncthreads();
    }

    float* gp = ws + ((size_t)(k * BATCH + b)) * P2 * P2;
    const int pr = pi * 96 + ty * 6;
    const int qc = qi * 96 + tx * 6;
#pragma unroll
    for (int i = 0; i < 6; i++)
#pragma unroll
        for (int j = 0; j < 6; j++)
            gp[(size_t)(pr + i) * P2 + qc + j] = acc[i][j];
}

// ---------------------------------------------------------------------------
// Kernel 2a: reduce Gpart over KSPLIT -> G[b][p][q]
// ---------------------------------------------------------------------------
__global__ __launch_bounds__(256) void k_gred(float* __restrict__ ws) {
    int i = blockIdx.x * 256 + threadIdx.x;      // over BATCH*P2*P2
    if (i >= SZ_G) return;
    int b  = i / (P2 * P2);
    int pq = i - b * (P2 * P2);
    float s = 0.0f;
#pragma unroll
    for (int k = 0; k < KSPLIT; k++)
        s += ws[((size_t)(k * BATCH + b)) * P2 * P2 + pq];
    ws[OFF_G + i] = s;
}

// ---------------------------------------------------------------------------
// Kernel 2b: M_h[c][c'] = sum_d Wq[h*64+d][c]*Wk[h*64+d][c']
//            P_h[o][c]  = sum_d Wout[o][h*64+d]*Wv[h*64+d][c]
// grid 8: blockIdx = which*4 + h
// ---------------------------------------------------------------------------
__global__ __launch_bounds__(256) void k_mp(const float* __restrict__ Wq,
                                            const float* __restrict__ Wk,
                                            const float* __restrict__ Wv,
                                            const float* __restrict__ Wout,
                                            float* __restrict__ ws) {
    const int h     = blockIdx.x & 3;
    const int which = blockIdx.x >> 2;
    const int tid   = threadIdx.x;
    for (int e = 0; e < 16; e++) {
        int id = e * 256 + tid;          // r*64 + c2
        int r  = id >> 6, c2 = id & 63;
        float s = 0.0f;
        if (which == 0) {
#pragma unroll 8
            for (int d = 0; d < 64; d++)
                s += Wq[(h * 64 + d) * 64 + r] * Wk[(h * 64 + d) * 64 + c2];
            ws[OFF_M + h * 4096 + id] = s;
        } else {
#pragma unroll 8
            for (int d = 0; d < 64; d++)
                s += Wout[r * 256 + h * 64 + d] * Wv[(h * 64 + d) * 64 + c2];
            ws[OFF_P + h * 4096 + id] = s;
        }
    }
}

// ---------------------------------------------------------------------------
// Kernel 2c: logits L[t][s] = sum_{c,c'} M_h[c][c'] * G[b][(c,t)][(c',s)];
//            softmax over s; write attnW[b][h][t][s]
// grid 32: blockIdx = b*4 + h
// ---------------------------------------------------------------------------
__global__ __launch_bounds__(256) void k_attn(float* __restrict__ ws) {
    const int b = blockIdx.x >> 2, h = blockIdx.x & 3;
    const int tid = threadIdx.x;
    const float* M = ws + OFF_M + h * 4096;
    const float* G = ws + OFF_G + (size_t)b * P2 * P2;

    float l[9];
#pragma unroll
    for (int i = 0; i < 9; i++) l[i] = 0.0f;

    for (int e = 0; e < 16; e++) {
        int id = e * 256 + tid;
        int c = id >> 6, c2 = id & 63;
        float m = M[id];
        const float* g0 = G + (size_t)(c * 3) * P2 + c2 * 3;
#pragma unroll
        for (int t = 0; t < 3; t++)
#pragma unroll
            for (int s = 0; s < 3; s++)
                l[t * 3 + s] = fmaf(m, g0[(size_t)t * P2 + s], l[t * 3 + s]);
    }

    __shared__ float red[9][256];
#pragma unroll
    for (int ts = 0; ts < 9; ts++) red[ts][tid] = l[ts];
    __syncthreads();
    for (int off = 128; off > 0; off >>= 1) {
        if (tid < off) {
#pragma unroll
            for (int ts = 0; ts < 9; ts++) red[ts][tid] += red[ts][tid + off];
        }
        __syncthreads();
    }
    if (tid == 0) {
        const float inv = 1.0f / sqrtf(192.0f);
        for (int t = 0; t < 3; t++) {
            float z0 = red[t * 3 + 0][0] * inv;
            float z1 = red[t * 3 + 1][0] * inv;
            float z2 = red[t * 3 + 2][0] * inv;
            float mx = fmaxf(z0, fmaxf(z1, z2));
            float e0 = expf(z0 - mx), e1 = expf(z1 - mx), e2 = expf(z2 - mx);
            float is = 1.0f / (e0 + e1 + e2);
            float* w = ws + OFF_W + (b * 4 + h) * 12 + t * 3;
            w[0] = e0 * is; w[1] = e1 * is; w[2] = e2 * is;
        }
    }
}

// ---------------------------------------------------------------------------
// Kernel 2d: AT[b][q2][p2] = sum_h attnW[b][h][t][s] * P_h[o][c]  + (p2==q2)
//            where p2 = o*3+t, q2 = c*3+s   (Abig transposed for coalesced loads)
// ---------------------------------------------------------------------------
__global__ __launch_bounds__(256) void k_abig(float* __restrict__ ws) {
    int i = blockIdx.x * 256 + threadIdx.x;      // over BATCH*P2*P2
    if (i >= SZ_G) return;
    int b  = i / (P2 * P2);
    int r  = i - b * (P2 * P2);
    int q2 = r / P2, p2 = r - q2 * P2;
    int o = p2 / 3, t = p2 - o * 3;
    int c = q2 / 3, s = q2 - c * 3;
    float acc = (p2 == q2) ? 1.0f : 0.0f;
#pragma unroll
    for (int h = 0; h < 4; h++)
        acc = fmaf(ws[OFF_W + (b * 4 + h) * 12 + t * 3 + s],
                   ws[OFF_P + h * 4096 + o * 64 + c], acc);
    ws[OFF_AT + i] = acc;
}

// ---------------------------------------------------------------------------
// Kernel 3: y[b][o][n][t] = sum_{q2} Abig[p2][q2] * feat[b][c][n][s],  p2=o*3+t
// Block: one (b, p2-half of 96, chunk of 64 points). LDS: At[192][96] + Xl[192][64]
// ---------------------------------------------------------------------------
__global__ __launch_bounds__(256) void k_apply(const float* __restrict__ feat,
                                               const float* __restrict__ ws,
                                               float* __restrict__ out) {
    const int bid  = blockIdx.x;
    const int nc   = bid & 127;
    const int half = (bid >> 7) & 1;
    const int b    = bid >> 8;
    const int n0   = nc * 64;

    __shared__ float At[P2][96];   // At[q2][p2_local]  (73.7 KB)
    __shared__ float Xl[P2][64];   // Xl[q2][nn]        (49.2 KB)

    const int tid = threadIdx.x;

    // load At: 192*96 = 18432 floats, coalesced from transposed Abig
    const float* ATg = ws + OFF_AT + (size_t)b * P2 * P2;
#pragma unroll 8
    for (int e = 0; e < 72; e++) {
        int idx = e * 256 + tid;
        int q = idx / 96, pl = idx - q * 96;
        At[q][pl] = ATg[(size_t)q * P2 + half * 96 + pl];
    }
    // load Xl: 64 channels x 64 points x float3
    const float* fb = feat + (size_t)b * CHN * NPTS * 3;
#pragma unroll 4
    for (int e = 0; e < 16; e++) {
        int idx = e * 256 + tid;
        int c = idx >> 6, nn = idx & 63;
        const float* src = fb + ((size_t)c * NPTS + n0 + nn) * 3;
        float v0 = src[0], v1 = src[1], v2 = src[2];
        Xl[c * 3 + 0][nn] = v0;
        Xl[c * 3 + 1][nn] = v1;
        Xl[c * 3 + 2][nn] = v2;
    }
    __syncthreads();

    const int ty = tid >> 4, tx = tid & 15;
    float acc[6][4];
#pragma unroll
    for (int i = 0; i < 6; i++)
#pragma unroll
        for (int j = 0; j < 4; j++) acc[i][j] = 0.0f;

#pragma unroll 4
    for (int q = 0; q < P2; q++) {
        float a[6], x[4];
#pragma unroll
        for (int i = 0; i < 6; i++) a[i] = At[q][ty * 6 + i];
#pragma unroll
        for (int j = 0; j < 4; j++) x[j] = Xl[q][tx * 4 + j];
#pragma unroll
        for (int i = 0; i < 6; i++)
#pragma unroll
            for (int j = 0; j < 4; j++)
                acc[i][j] = fmaf(a[i], x[j], acc[i][j]);
    }

    // write out: rows p2base..+5 = two channels (o0,o0+1) x t{0,1,2}
    const int p2base = half * 96 + ty * 6;
    const int o0 = p2base / 3;
    float* ob = out + (size_t)b * CHN * NPTS * 3;
#pragma unroll
    for (int j = 0; j < 4; j++) {
        int n = n0 + tx * 4 + j;
        float* pp = ob + ((size_t)o0 * NPTS + n) * 3;
        pp[0] = acc[0][j]; pp[1] = acc[1][j]; pp[2] = acc[2][j];
        float* pp2 = ob + ((size_t)(o0 + 1) * NPTS + n) * 3;
        pp2[0] = acc[3][j]; pp2[1] = acc[4][j]; pp2[2] = acc[5][j];
    }
}

extern "C" void kernel_launch(void* const* d_in, const int* in_sizes, int n_in,
                              void* d_out, int out_size, void* d_ws, size_t ws_size,
                              hipStream_t stream) {
    const float* feat = (const float*)d_in[0];
    // d_in[1] = xyz (unused by the reference computation)
    const float* Wq   = (const float*)d_in[2];
    const float* Wk   = (const float*)d_in[3];
    const float* Wv   = (const float*)d_in[4];
    const float* Wout = (const float*)d_in[5];
    float* out = (float*)d_out;
    float* wsf = (float*)d_ws;

    // 1. Gram partials: 8 b x 4 tiles x 16 k-chunks
    k_gram<<<BATCH * 4 * KSPLIT, 256, 0, stream>>>(feat, wsf);
    // 2b. M/P weight products (independent of k_gram, tiny)
    k_mp<<<8, 256, 0, stream>>>(Wq, Wk, Wv, Wout, wsf);
    // 2a. reduce partials
    k_gred<<<(SZ_G + 255) / 256, 256, 0, stream>>>(wsf);
    // 2c. logits + softmax
    k_attn<<<BATCH * NH, 256, 0, stream>>>(wsf);
    // 2d. build (I + Abig)^T
    k_abig<<<(SZ_G + 255) / 256, 256, 0, stream>>>(wsf);
    // 3. apply per-point 192x192 map
    k_apply<<<BATCH * 2 * 128, 256, 0, stream>>>(feat, wsf, out);
}

// Round 2
// 216.042 us; speedup vs baseline: 1.2691x; 1.2691x over previous
//
#include <hip/hip_runtime.h>
#include <math.h>

// Problem constants
#define BATCH 8
#define CHN   64
#define NPTS  8192
#define NH    4
#define P2    192                 // combined (channel, xyz) index = 64*3
#define SZ_G  (BATCH * P2 * P2)   // 294,912 floats

// ---------------------------------------------------------------------------
// Kernel 1: symmetric Gram tiles.
//   G[b][p][q] = sum_n F2[b][p][n]*F2[b][q][n], F2[b][c*3+t][n] = feat[b][c][n][t]
// 3 tiles per (b, k-chunk): tile0=(0,0), tile1=(0,1), tile2=(1,1) of 96x96.
// Block: 256 thr, 6x6 accs/thread, KT=32 points staged per step.
// ---------------------------------------------------------------------------
__global__ __launch_bounds__(256, 4) void k_gram(const float* __restrict__ feat,
                                                 float* __restrict__ tp,
                                                 int ksplit, int kch) {
    const int bid  = blockIdx.x;
    const int k    = bid % ksplit;
    const int tile = (bid / ksplit) % 3;
    const int b    = bid / (3 * ksplit);
    const int pi   = (tile == 2) ? 1 : 0;
    const int qi   = (tile == 0) ? 0 : 1;
    const int diag = (tile != 1);
    const int n0   = k * kch;

    __shared__ float Ap[32][100];   // [kk][ch_local*3 + t], pad 96->100 (16B-aligned rows)
    __shared__ float Bp[32][100];

    const int tid = threadIdx.x;
    const int ty = tid >> 4, tx = tid & 15;

    float acc[6][6];
#pragma unroll
    for (int i = 0; i < 6; i++)
#pragma unroll
        for (int j = 0; j < 6; j++) acc[i][j] = 0.0f;

    const float* fb = feat + (size_t)b * CHN * NPTS * 3;
    const int nf4 = diag ? 768 : 1536;    // float4s to stage per step

    for (int ks = 0; ks < kch; ks += 32) {
        // stage: per panel 32 channel-rows x 96 floats (=32 pts x 3) = 768 float4
        for (int idx = tid; idx < nf4; idx += 256) {
            int panel = idx / 768;
            int wi    = idx - panel * 768;
            int r     = wi / 24;            // local channel row
            int j     = wi - r * 24;        // float4 within row
            int cg    = (panel ? qi : pi) * 32 + r;
            const float4 v = *(const float4*)(fb + ((size_t)cg * NPTS + (size_t)(n0 + ks)) * 3 + j * 4);
            float vv[4] = {v.x, v.y, v.z, v.w};
            float* dst = panel ? &Bp[0][0] : &Ap[0][0];
            int e0 = j * 4;
#pragma unroll
            for (int u = 0; u < 4; u++) {
                int kk = (e0 + u) / 3;
                int t  = (e0 + u) - kk * 3;
                dst[kk * 100 + r * 3 + t] = vv[u];
            }
        }
        __syncthreads();
        const float (*Bq)[100] = diag ? Ap : Bp;
#pragma unroll 4
        for (int kk = 0; kk < 32; kk++) {
            float a[6], bb[6];
#pragma unroll
            for (int i = 0; i < 6; i++) a[i] = Ap[kk][ty * 6 + i];
#pragma unroll
            for (int j = 0; j < 6; j++) bb[j] = Bq[kk][tx * 6 + j];
#pragma unroll
            for (int i = 0; i < 6; i++)
#pragma unroll
                for (int j = 0; j < 6; j++)
                    acc[i][j] = fmaf(a[i], bb[j], acc[i][j]);
        }
        __syncthreads();
    }

    float* gp = tp + ((size_t)(k * BATCH + b) * 3 + tile) * 9216;
#pragma unroll
    for (int i = 0; i < 6; i++)
#pragma unroll
        for (int j = 0; j < 6; j++)
            gp[(ty * 6 + i) * 96 + tx * 6 + j] = acc[i][j];
}

// ---------------------------------------------------------------------------
// Kernel 2a: reduce tile partials over ksplit -> full G[b][192][192]
// (lower-left quadrant read transposed from tile1)
// ---------------------------------------------------------------------------
__global__ __launch_bounds__(256) void k_gred(const float* __restrict__ tp,
                                              float* __restrict__ g, int ksplit) {
    int i = blockIdx.x * 256 + threadIdx.x;
    if (i >= SZ_G) return;
    int b = i / (P2 * P2);
    int r = i - b * (P2 * P2);
    int p = r / P2, q = r - (r / P2) * P2;
    int tile, el;
    if (p < 96) {
        if (q < 96) { tile = 0; el = p * 96 + q; }
        else        { tile = 1; el = p * 96 + (q - 96); }
    } else {
        if (q < 96) { tile = 1; el = q * 96 + (p - 96); }   // symmetric transpose
        else        { tile = 2; el = (p - 96) * 96 + (q - 96); }
    }
    float s = 0.0f;
    for (int kk = 0; kk < ksplit; kk++)
        s += tp[((size_t)(kk * BATCH + b) * 3 + tile) * 9216 + el];
    g[i] = s;
}

// ---------------------------------------------------------------------------
// Kernel 2b: M_h[c][c'] = sum_d Wq[h*64+d][c]*Wk[h*64+d][c']
//            P_h[o][c]  = sum_d Wout[o][h*64+d]*Wv[h*64+d][c]
// ---------------------------------------------------------------------------
__global__ __launch_bounds__(256) void k_mp(const float* __restrict__ Wq,
                                            const float* __restrict__ Wk,
                                            const float* __restrict__ Wv,
                                            const float* __restrict__ Wout,
                                            float* __restrict__ m,
                                            float* __restrict__ pP) {
    const int h     = blockIdx.x & 3;
    const int which = blockIdx.x >> 2;
    const int tid   = threadIdx.x;
    for (int e = 0; e < 16; e++) {
        int id = e * 256 + tid;
        int r  = id >> 6, c2 = id & 63;
        float s = 0.0f;
        if (which == 0) {
#pragma unroll 8
            for (int d = 0; d < 64; d++)
                s += Wq[(h * 64 + d) * 64 + r] * Wk[(h * 64 + d) * 64 + c2];
            m[h * 4096 + id] = s;
        } else {
#pragma unroll 8
            for (int d = 0; d < 64; d++)
                s += Wout[r * 256 + h * 64 + d] * Wv[(h * 64 + d) * 64 + c2];
            pP[h * 4096 + id] = s;
        }
    }
}

// ---------------------------------------------------------------------------
// Kernel 2c: logits + softmax -> attn weights w[b][h][t][s]
// ---------------------------------------------------------------------------
__global__ __launch_bounds__(256) void k_attn(const float* __restrict__ g,
                                              const float* __restrict__ m,
                                              float* __restrict__ w) {
    const int b = blockIdx.x >> 2, h = blockIdx.x & 3;
    const int tid = threadIdx.x;
    const float* M = m + h * 4096;
    const float* G = g + (size_t)b * P2 * P2;

    float l[9];
#pragma unroll
    for (int i = 0; i < 9; i++) l[i] = 0.0f;

    for (int e = 0; e < 16; e++) {
        int id = e * 256 + tid;
        int c = id >> 6, c2 = id & 63;
        float mm = M[id];
        const float* g0 = G + (size_t)(c * 3) * P2 + c2 * 3;
#pragma unroll
        for (int t = 0; t < 3; t++)
#pragma unroll
            for (int s = 0; s < 3; s++)
                l[t * 3 + s] = fmaf(mm, g0[(size_t)t * P2 + s], l[t * 3 + s]);
    }

    __shared__ float red[9][256];
#pragma unroll
    for (int ts = 0; ts < 9; ts++) red[ts][tid] = l[ts];
    __syncthreads();
    for (int off = 128; off > 0; off >>= 1) {
        if (tid < off) {
#pragma unroll
            for (int ts = 0; ts < 9; ts++) red[ts][tid] += red[ts][tid + off];
        }
        __syncthreads();
    }
    if (tid == 0) {
        const float inv = 1.0f / sqrtf(192.0f);
        for (int t = 0; t < 3; t++) {
            float z0 = red[t * 3 + 0][0] * inv;
            float z1 = red[t * 3 + 1][0] * inv;
            float z2 = red[t * 3 + 2][0] * inv;
            float mx = fmaxf(z0, fmaxf(z1, z2));
            float e0 = expf(z0 - mx), e1 = expf(z1 - mx), e2 = expf(z2 - mx);
            float is = 1.0f / (e0 + e1 + e2);
            float* wp = w + (b * 4 + h) * 12 + t * 3;
            wp[0] = e0 * is; wp[1] = e1 * is; wp[2] = e2 * is;
        }
    }
}

// ---------------------------------------------------------------------------
// Kernel 2d: AT[b][q2][p2] = sum_h w[b][h][t][s]*P_h[o][c] + (p2==q2)
//   p2 = o*3+t, q2 = c*3+s
// ---------------------------------------------------------------------------
__global__ __launch_bounds__(256) void k_abig(const float* __restrict__ w,
                                              const float* __restrict__ pP,
                                              float* __restrict__ at) {
    int i = blockIdx.x * 256 + threadIdx.x;
    if (i >= SZ_G) return;
    int b  = i / (P2 * P2);
    int r  = i - b * (P2 * P2);
    int q2 = r / P2, p2 = r - q2 * P2;
    int o = p2 / 3, t = p2 - o * 3;
    int c = q2 / 3, s = q2 - c * 3;
    float acc = (p2 == q2) ? 1.0f : 0.0f;
#pragma unroll
    for (int h = 0; h < 4; h++)
        acc = fmaf(w[(b * 4 + h) * 12 + t * 3 + s], pP[h * 4096 + o * 64 + c], acc);
    at[i] = acc;
}

// ---------------------------------------------------------------------------
// Kernel 3: out[b][o][n][t] = sum_q2 AT[q2][p2]*X[q2][n],  p2=o*3+t,
//   X[c*3+s][n] = feat[b][c][n][s].  Block: 192 rows x 64 points, K-tiled 24.
// ---------------------------------------------------------------------------
__global__ __launch_bounds__(256, 4) void k_apply(const float* __restrict__ feat,
                                                  const float* __restrict__ at,
                                                  float* __restrict__ out) {
    const int bid = blockIdx.x;
    const int nc  = bid & 127;
    const int b   = bid >> 7;
    const int n0  = nc * 64;

    __shared__ float At[24][196];   // [q_local][p2], pad 192->196 (rows 16B-aligned)
    __shared__ float Xt[24][72];    // [q_local][nn], pad 64->72

    const int tid = threadIdx.x;
    const int ty = tid >> 4, tx = tid & 15;

    const float* ATg = at + (size_t)b * P2 * P2;
    const float* fb  = feat + (size_t)b * CHN * NPTS * 3;

    float acc[12][4];
#pragma unroll
    for (int i = 0; i < 12; i++)
#pragma unroll
        for (int u = 0; u < 4; u++) acc[i][u] = 0.0f;

    for (int q0 = 0; q0 < P2; q0 += 24) {
        // stage A rows q0..q0+23 (full 192 cols): 24*48 = 1152 float4
        for (int idx = tid; idx < 1152; idx += 256) {
            int q = idx / 48, j = idx - (idx / 48) * 48;
            float4 v = *(const float4*)(ATg + (size_t)(q0 + q) * P2 + j * 4);
            *(float4*)&At[q][j * 4] = v;
        }
        // stage X: 8 channels x 64 pts x 3 = 384 float4, transpose (n,t)->[q][nn]
        int c0 = q0 / 3;
        for (int idx = tid; idx < 384; idx += 256) {
            int cl = idx / 48, j = idx - (idx / 48) * 48;
            const float4 v = *(const float4*)(fb + ((size_t)(c0 + cl) * NPTS + n0) * 3 + j * 4);
            float vv[4] = {v.x, v.y, v.z, v.w};
            int e0 = j * 4;
#pragma unroll
            for (int u = 0; u < 4; u++) {
                int nn = (e0 + u) / 3;
                int t  = (e0 + u) - nn * 3;
                Xt[cl * 3 + t][nn] = vv[u];
            }
        }
        __syncthreads();
#pragma unroll 4
        for (int kk = 0; kk < 24; kk++) {
            float x[4], a[12];
#pragma unroll
            for (int u = 0; u < 4; u++) x[u] = Xt[kk][tx * 4 + u];
#pragma unroll
            for (int i = 0; i < 12; i++) a[i] = At[kk][ty * 12 + i];
#pragma unroll
            for (int i = 0; i < 12; i++)
#pragma unroll
                for (int u = 0; u < 4; u++)
                    acc[i][u] = fmaf(a[i], x[u], acc[i][u]);
        }
        __syncthreads();
    }

    float* ob = out + (size_t)b * CHN * NPTS * 3;
#pragma unroll
    for (int i = 0; i < 12; i++) {
        int p2r = ty * 12 + i;
        int o = p2r / 3, t = p2r - (p2r / 3) * 3;
#pragma unroll
        for (int u = 0; u < 4; u++) {
            int n = n0 + tx * 4 + u;
            ob[((size_t)o * NPTS + n) * 3 + t] = acc[i][u];
        }
    }
}

extern "C" void kernel_launch(void* const* d_in, const int* in_sizes, int n_in,
                              void* d_out, int out_size, void* d_ws, size_t ws_size,
                              hipStream_t stream) {
    const float* feat = (const float*)d_in[0];
    // d_in[1] = xyz (unused by the reference computation)
    const float* Wq   = (const float*)d_in[2];
    const float* Wk   = (const float*)d_in[3];
    const float* Wv   = (const float*)d_in[4];
    const float* Wout = (const float*)d_in[5];
    float* out = (float*)d_out;
    float* wsf = (float*)d_ws;

    // pick KSPLIT by available workspace (32 needs ~30.8 MB; 16 needs ~16.6 MB)
    size_t need32_fl = (size_t)32 * BATCH * 3 * 9216 + SZ_G + 2 * NH * 4096
                     + BATCH * NH * 12 + SZ_G;
    int ksplit = (ws_size >= need32_fl * sizeof(float)) ? 32 : 16;
    int kch = NPTS / ksplit;

    float* tp  = wsf;
    float* g   = tp + (size_t)ksplit * BATCH * 3 * 9216;
    float* m   = g + SZ_G;
    float* pP  = m + NH * 4096;
    float* w   = pP + NH * 4096;
    float* atb = w + BATCH * NH * 12;

    k_gram<<<BATCH * 3 * ksplit, 256, 0, stream>>>(feat, tp, ksplit, kch);
    k_mp<<<8, 256, 0, stream>>>(Wq, Wk, Wv, Wout, m, pP);
    k_gred<<<(SZ_G + 255) / 256, 256, 0, stream>>>(tp, g, ksplit);
    k_attn<<<BATCH * NH, 256, 0, stream>>>(g, m, w);
    k_abig<<<(SZ_G + 255) / 256, 256, 0, stream>>>(w, pP, atb);
    k_apply<<<BATCH * 128, 256, 0, stream>>>(feat, atb, out);
}

// Round 3
// 138.816 us; speedup vs baseline: 1.9751x; 1.5563x over previous
//
#include <hip/hip_runtime.h>
#include <math.h>

typedef _Float16 f16;
typedef _Float16 f16x8 __attribute__((ext_vector_type(8)));
typedef float f32x4 __attribute__((ext_vector_type(4)));

#define BATCH 8
#define CHN   64
#define NPTS  8192
#define NH    4
#define P2    192
#define GG    (P2 * P2)          // 36864
#define KS_GRAM 8                // launch chunks; x2 wave-groups -> 16 partials

// ---------------------------------------------------------------------------
// k_mp: M_h[c][c'] = sum_d Wq[h64+d][c]*Wk[h64+d][c']  (fp32)
//       P_h[o][c]  = sum_d Wout[o][h64+d]*Wv[h64+d][c]
// ---------------------------------------------------------------------------
__global__ __launch_bounds__(256) void k_mp(const float* __restrict__ Wq,
                                            const float* __restrict__ Wk,
                                            const float* __restrict__ Wv,
                                            const float* __restrict__ Wout,
                                            float* __restrict__ M,
                                            float* __restrict__ P) {
    const int h     = blockIdx.x & 3;
    const int which = blockIdx.x >> 2;
    const int tid   = threadIdx.x;
    for (int e = 0; e < 16; e++) {
        int id = e * 256 + tid;
        int r  = id >> 6, c2 = id & 63;
        float s = 0.0f;
        if (which == 0) {
#pragma unroll 8
            for (int d = 0; d < 64; d++)
                s += Wq[(h * 64 + d) * 64 + r] * Wk[(h * 64 + d) * 64 + c2];
            M[h * 4096 + id] = s;
        } else {
#pragma unroll 8
            for (int d = 0; d < 64; d++)
                s += Wout[r * 256 + h * 64 + d] * Wv[(h * 64 + d) * 64 + c2];
            P[h * 4096 + id] = s;
        }
    }
}

// ---------------------------------------------------------------------------
// k_prepF: F2h[b][(c*3+t)][n] = fp16(feat[b][c][n][t])   (n-contiguous rows)
// block: 64-n chunk x all 192 rows, via LDS transpose tile [192][72]
// ---------------------------------------------------------------------------
__global__ __launch_bounds__(256) void k_prepF(const float* __restrict__ feat,
                                               f16* __restrict__ f2h) {
    const int nc = blockIdx.x & 127;
    const int b  = blockIdx.x >> 7;
    const int n0 = nc * 64;
    __shared__ f16 T[P2][72];
    const int tid = threadIdx.x;
    const float* fb = feat + (size_t)b * CHN * NPTS * 3;
    for (int idx = tid; idx < 3072; idx += 256) {   // 64 ch x 48 float4
        int c = idx / 48, j = idx - (idx / 48) * 48;
        float4 v = *(const float4*)(fb + ((size_t)c * NPTS + n0) * 3 + j * 4);
        float vv[4] = {v.x, v.y, v.z, v.w};
        int e0 = j * 4;
#pragma unroll
        for (int u = 0; u < 4; u++) {
            int nn = (e0 + u) / 3, s = (e0 + u) - ((e0 + u) / 3) * 3;
            T[c * 3 + s][nn] = (f16)vv[u];
        }
    }
    __syncthreads();
    f16* dst = f2h + (size_t)b * P2 * NPTS + n0;
    for (int idx = tid; idx < 1536; idx += 256) {   // 192 rows x 8 x (8 halves)
        int r = idx >> 3, u = idx & 7;
        *(f16x8*)(dst + (size_t)r * NPTS + u * 8) = *(const f16x8*)&T[r][u * 8];
    }
}

// ---------------------------------------------------------------------------
// k_prepT: featT[b][n_local][(c*3+s)] = fp16(feat[b][c][half*4096+n_local][s])
// one n-half at a time (ws budget). LDS tile [64 n][200]
// ---------------------------------------------------------------------------
__global__ __launch_bounds__(256) void k_prepT(const float* __restrict__ feat,
                                               f16* __restrict__ ft, int half) {
    const int nc = blockIdx.x & 63;
    const int b  = blockIdx.x >> 6;
    const int n0 = half * 4096 + nc * 64;
    __shared__ f16 T[64][200];
    const int tid = threadIdx.x;
    const float* fb = feat + (size_t)b * CHN * NPTS * 3;
    for (int idx = tid; idx < 3072; idx += 256) {
        int c = idx / 48, j = idx - (idx / 48) * 48;
        float4 v = *(const float4*)(fb + ((size_t)c * NPTS + n0) * 3 + j * 4);
        float vv[4] = {v.x, v.y, v.z, v.w};
        int e0 = j * 4;
#pragma unroll
        for (int u = 0; u < 4; u++) {
            int nn = (e0 + u) / 3, s = (e0 + u) - ((e0 + u) / 3) * 3;
            T[nn][c * 3 + s] = (f16)vv[u];
        }
    }
    __syncthreads();
    f16* dst = ft + ((size_t)b * 4096 + nc * 64) * P2;
    for (int idx = tid; idx < 1536; idx += 256) {   // 64 rows x 24 x (8 halves)
        int r = idx / 24, u = idx - (idx / 24) * 24;
        *(f16x8*)(dst + (size_t)r * P2 + u * 8) = *(const f16x8*)&T[r][u * 8];
    }
}

// ---------------------------------------------------------------------------
// k_gram: Sp[keff][b][p][q] = sum_{n in chunk} F2h[p][n]*F2h[q][n]  via MFMA.
// 512 thr = 8 waves = 2 groups x 4 quadrant-waves. Each group: own 512-pt
// k-subchunk, own LDS double-buffered [192][32] tile (XOR-swizzled chunks).
// ---------------------------------------------------------------------------
__global__ __launch_bounds__(512, 2) void k_gram(const f16* __restrict__ f2h,
                                                 float* __restrict__ sp) {
    const int k   = blockIdx.x & 7;
    const int b   = blockIdx.x >> 3;
    const int tid = threadIdx.x;
    const int wid = tid >> 6, lane = tid & 63;
    const int g   = wid >> 2;                  // wave-group (k sub-chunk)
    const int qw  = wid & 3;                   // quadrant
    const int qp  = (qw >> 1) * 96, qq = (qw & 1) * 96;
    const int l15 = lane & 15, l4 = lane >> 4;
    const int ltid = tid & 255;                // tid within group

    __shared__ f16 T[2][2][192 * 32];          // [group][buf][row*32 + slot*8]

    const f16* src = f2h + (size_t)b * P2 * NPTS + (size_t)(k * 2 + g) * 512;

    f32x4 acc[6][6];
#pragma unroll
    for (int i = 0; i < 6; i++)
#pragma unroll
        for (int j = 0; j < 6; j++) acc[i][j] = (f32x4){0.f, 0.f, 0.f, 0.f};

    // prolog: stage ks=0
#pragma unroll
    for (int i = 0; i < 3; i++) {
        int idx = ltid + i * 256;              // 768 16B-units: row*4+chunk
        int row = idx >> 2, ch = idx & 3;
        f16x8 v = *(const f16x8*)(src + (size_t)row * NPTS + ch * 8);
        T[g][0][row * 32 + (ch ^ (row & 3)) * 8] = v[0];  // placeholder overwritten below
        *(f16x8*)&T[g][0][row * 32 + (ch ^ (row & 3)) * 8] = v;
    }
    __syncthreads();

    for (int ks = 0; ks < 16; ks++) {
        const int buf = ks & 1;
        // issue next-tile global loads early (T14)
        f16x8 stg[3];
        if (ks < 15) {
#pragma unroll
            for (int i = 0; i < 3; i++) {
                int idx = ltid + i * 256;
                int row = idx >> 2, ch = idx & 3;
                stg[i] = *(const f16x8*)(src + (size_t)row * NPTS + (ks + 1) * 32 + ch * 8);
            }
        }
        // fragments from current buffer
        f16x8 af[6], bf[6];
#pragma unroll
        for (int mt = 0; mt < 6; mt++) {
            int row = qp + mt * 16 + l15;
            af[mt] = *(const f16x8*)&T[g][buf][row * 32 + ((l4 ^ (row & 3)) * 8)];
        }
#pragma unroll
        for (int nt = 0; nt < 6; nt++) {
            int row = qq + nt * 16 + l15;
            bf[nt] = *(const f16x8*)&T[g][buf][row * 32 + ((l4 ^ (row & 3)) * 8)];
        }
#pragma unroll
        for (int mt = 0; mt < 6; mt++)
#pragma unroll
            for (int nt = 0; nt < 6; nt++)
                acc[mt][nt] = __builtin_amdgcn_mfma_f32_16x16x32_f16(af[mt], bf[nt], acc[mt][nt], 0, 0, 0);
        // write staged tile late
        if (ks < 15) {
#pragma unroll
            for (int i = 0; i < 3; i++) {
                int idx = ltid + i * 256;
                int row = idx >> 2, ch = idx & 3;
                *(f16x8*)&T[g][buf ^ 1][row * 32 + (ch ^ (row & 3)) * 8] = stg[i];
            }
        }
        __syncthreads();
    }

    float* out = sp + ((size_t)((k * 2 + g) * BATCH + b)) * GG;
#pragma unroll
    for (int mt = 0; mt < 6; mt++)
#pragma unroll
        for (int nt = 0; nt < 6; nt++)
#pragma unroll
            for (int r = 0; r < 4; r++) {
                int p = qp + mt * 16 + l4 * 4 + r;
                int q = qq + nt * 16 + l15;
                out[(size_t)p * P2 + q] = acc[mt][nt][r];
            }
}

// ---------------------------------------------------------------------------
// k_gred: G[b][pq] = sum over 16 partials
// ---------------------------------------------------------------------------
__global__ __launch_bounds__(256) void k_gred(const float* __restrict__ sp,
                                              float* __restrict__ gbuf) {
    int i = blockIdx.x * 256 + threadIdx.x;
    if (i >= BATCH * GG) return;
    int b = i / GG, pq = i - b * GG;
    float s = 0.0f;
#pragma unroll
    for (int kk = 0; kk < 16; kk++)
        s += sp[((size_t)(kk * BATCH + b)) * GG + pq];
    gbuf[i] = s;
}

// ---------------------------------------------------------------------------
// k_attn: logits + softmax -> w[b][h][t][s]
// ---------------------------------------------------------------------------
__global__ __launch_bounds__(256) void k_attn(const float* __restrict__ gbuf,
                                              const float* __restrict__ M,
                                              float* __restrict__ w) {
    const int b = blockIdx.x >> 2, h = blockIdx.x & 3;
    const int tid = threadIdx.x;
    const float* Mh = M + h * 4096;
    const float* G  = gbuf + (size_t)b * GG;

    float l[9];
#pragma unroll
    for (int i = 0; i < 9; i++) l[i] = 0.0f;

    for (int e = 0; e < 16; e++) {
        int id = e * 256 + tid;
        int c = id >> 6, c2 = id & 63;
        float mm = Mh[id];
        const float* g0 = G + (size_t)(c * 3) * P2 + c2 * 3;
#pragma unroll
        for (int t = 0; t < 3; t++)
#pragma unroll
            for (int s = 0; s < 3; s++)
                l[t * 3 + s] = fmaf(mm, g0[(size_t)t * P2 + s], l[t * 3 + s]);
    }

    __shared__ float red[9][256];
#pragma unroll
    for (int ts = 0; ts < 9; ts++) red[ts][tid] = l[ts];
    __syncthreads();
    for (int off = 128; off > 0; off >>= 1) {
        if (tid < off) {
#pragma unroll
            for (int ts = 0; ts < 9; ts++) red[ts][tid] += red[ts][tid + off];
        }
        __syncthreads();
    }
    if (tid == 0) {
        const float inv = 1.0f / sqrtf(192.0f);
        for (int t = 0; t < 3; t++) {
            float z0 = red[t * 3 + 0][0] * inv;
            float z1 = red[t * 3 + 1][0] * inv;
            float z2 = red[t * 3 + 2][0] * inv;
            float mx = fmaxf(z0, fmaxf(z1, z2));
            float e0 = expf(z0 - mx), e1 = expf(z1 - mx), e2 = expf(z2 - mx);
            float is = 1.0f / (e0 + e1 + e2);
            float* wp = w + (b * 4 + h) * 12 + t * 3;
            wp[0] = e0 * is; wp[1] = e1 * is; wp[2] = e2 * is;
        }
    }
}

// ---------------------------------------------------------------------------
// k_abig: Ab[b][p2][q2] = fp16( sum_h w[b][h][t][s]*P_h[o][c] )   (NO identity)
// p2 = o*3+t, q2 = c*3+s
// ---------------------------------------------------------------------------
__global__ __launch_bounds__(256) void k_abig(const float* __restrict__ w,
                                              const float* __restrict__ P,
                                              f16* __restrict__ ab) {
    int i = blockIdx.x * 256 + threadIdx.x;
    if (i >= BATCH * GG) return;
    int b  = i / GG;
    int rr = i - b * GG;
    int p2 = rr / P2, q2 = rr - (rr / P2) * P2;
    int o = p2 / 3, t = p2 - (p2 / 3) * 3;
    int c = q2 / 3, s = q2 - (q2 / 3) * 3;
    float acc = 0.0f;
#pragma unroll
    for (int h = 0; h < 4; h++)
        acc = fmaf(w[(b * 4 + h) * 12 + t * 3 + s], P[h * 4096 + o * 64 + c], acc);
    ab[(size_t)b * GG + (size_t)p2 * P2 + q2] = (f16)acc;
}

// ---------------------------------------------------------------------------
// k_apply: out[b][o][n][t] = feat[...] + sum_q2 Ab[p2][q2]*featT[n][q2]
// MFMA, no LDS. Block: 4 waves (M-split 4x48), 32-n tile. Grid: b x 128 nb.
// ---------------------------------------------------------------------------
__global__ __launch_bounds__(256, 4) void k_apply(const float* __restrict__ feat,
                                                  const f16* __restrict__ ft,
                                                  const f16* __restrict__ ab,
                                                  float* __restrict__ out, int half) {
    const int nb = blockIdx.x & 127;
    const int b  = blockIdx.x >> 7;
    const int tid = threadIdx.x;
    const int wid = tid >> 6, lane = tid & 63;
    const int l15 = lane & 15, l4 = lane >> 4;
    const int nloc0 = nb * 32;                 // local n within half

    const f16* A  = ab + (size_t)b * GG;
    const f16* X  = ft + (size_t)b * 4096 * P2;

    f32x4 acc[3][2];
#pragma unroll
    for (int i = 0; i < 3; i++)
#pragma unroll
        for (int j = 0; j < 2; j++) acc[i][j] = (f32x4){0.f, 0.f, 0.f, 0.f};

#pragma unroll
    for (int ks = 0; ks < 6; ks++) {
        f16x8 af[3], bf[2];
#pragma unroll
        for (int mt = 0; mt < 3; mt++) {
            int p2 = wid * 48 + mt * 16 + l15;
            af[mt] = *(const f16x8*)(A + (size_t)p2 * P2 + ks * 32 + l4 * 8);
        }
#pragma unroll
        for (int nt = 0; nt < 2; nt++) {
            int nl = nloc0 + nt * 16 + l15;
            bf[nt] = *(const f16x8*)(X + (size_t)nl * P2 + ks * 32 + l4 * 8);
        }
#pragma unroll
        for (int mt = 0; mt < 3; mt++)
#pragma unroll
            for (int nt = 0; nt < 2; nt++)
                acc[mt][nt] = __builtin_amdgcn_mfma_f32_16x16x32_f16(af[mt], bf[nt], acc[mt][nt], 0, 0, 0);
    }

    const float* fb = feat + (size_t)b * CHN * NPTS * 3;
    float* ob = out + (size_t)b * CHN * NPTS * 3;
#pragma unroll
    for (int mt = 0; mt < 3; mt++)
#pragma unroll
        for (int nt = 0; nt < 2; nt++)
#pragma unroll
            for (int r = 0; r < 4; r++) {
                int p2 = wid * 48 + mt * 16 + l4 * 4 + r;
                int n  = half * 4096 + nloc0 + nt * 16 + l15;
                int o = p2 / 3, t = p2 - (p2 / 3) * 3;
                size_t off = ((size_t)o * NPTS + n) * 3 + t;
                ob[off] = fb[off] + acc[mt][nt][r];
            }
}

extern "C" void kernel_launch(void* const* d_in, const int* in_sizes, int n_in,
                              void* d_out, int out_size, void* d_ws, size_t ws_size,
                              hipStream_t stream) {
    const float* feat = (const float*)d_in[0];
    const float* Wq   = (const float*)d_in[2];
    const float* Wk   = (const float*)d_in[3];
    const float* Wv   = (const float*)d_in[4];
    const float* Wout = (const float*)d_in[5];
    float* out = (float*)d_out;

    // d_out doubles as early-phase scratch (dead before k_apply overwrites it):
    f16*   f2h = (f16*)d_out;                              // 25,165,824 B
    float* sp  = (float*)((char*)d_out + 25165824);        // 18,874,368 B (<=50.3MB total)

    char* w8 = (char*)d_ws;                                // ws usage: ~14.5 MB
    f16*   ft = (f16*)w8;                                  // 12,582,912
    float* G  = (float*)(w8 + 12582912);                   // 1,179,648
    float* M  = (float*)(w8 + 13762560);                   // 65,536
    float* P  = (float*)(w8 + 13828096);                   // 65,536
    float* w  = (float*)(w8 + 13893632);                   // 1,536
    f16*   Ab = (f16*)(w8 + 13895168);                     // 589,824

    k_mp   <<<8,    256, 0, stream>>>(Wq, Wk, Wv, Wout, M, P);
    k_prepF<<<1024, 256, 0, stream>>>(feat, f2h);
    k_gram <<<64,   512, 0, stream>>>(f2h, sp);
    k_gred <<<1152, 256, 0, stream>>>(sp, G);
    k_attn <<<32,   256, 0, stream>>>(G, M, w);
    k_abig <<<1152, 256, 0, stream>>>(w, P, Ab);
    for (int h = 0; h < 2; h++) {
        k_prepT<<<512,  256, 0, stream>>>(feat, ft, h);
        k_apply<<<1024, 256, 0, stream>>>(feat, ft, Ab, out, h);
    }
}

// Round 4
// 98.553 us; speedup vs baseline: 2.7820x; 1.4085x over previous
//
#include <hip/hip_runtime.h>
#include <math.h>

typedef _Float16 f16;
typedef _Float16 f16x8 __attribute__((ext_vector_type(8)));
typedef _Float16 f16x4 __attribute__((ext_vector_type(4)));
typedef float f32x4 __attribute__((ext_vector_type(4)));

#define BATCH 8
#define CHN   64
#define NPTS  8192
#define P2    192
#define GG    (P2 * P2)   // 36864

// ---------------------------------------------------------------------------
// k_mp: MS[c][c2][h] = sum_d Wq[h64+d][c]*Wk[h64+d][c2]   (h-contiguous float4)
//       P[h][o][c]   = sum_d Wout[o][h64+d]*Wv[h64+d][c]
// block 0 also zeroes the logit accumulator.
// ---------------------------------------------------------------------------
__global__ __launch_bounds__(256) void k_mp(const float* __restrict__ Wq,
                                            const float* __restrict__ Wk,
                                            const float* __restrict__ Wv,
                                            const float* __restrict__ Wout,
                                            float* __restrict__ MS,
                                            float* __restrict__ P,
                                            float* __restrict__ logits) {
    const int h     = blockIdx.x & 3;
    const int which = blockIdx.x >> 2;
    const int tid   = threadIdx.x;
    if (blockIdx.x == 0) {
        for (int i = tid; i < BATCH * 36; i += 256) logits[i] = 0.0f;
    }
    for (int e = 0; e < 16; e++) {
        int id = e * 256 + tid;          // id = r*64 + c2
        int r  = id >> 6, c2 = id & 63;
        float s = 0.0f;
        if (which == 0) {
#pragma unroll 8
            for (int d = 0; d < 64; d++)
                s += Wq[(h * 64 + d) * 64 + r] * Wk[(h * 64 + d) * 64 + c2];
            MS[(size_t)id * 4 + h] = s;
        } else {
#pragma unroll 8
            for (int d = 0; d < 64; d++)
                s += Wout[r * 256 + h * 64 + d] * Wv[(h * 64 + d) * 64 + c2];
            P[h * 4096 + id] = s;
        }
    }
}

// ---------------------------------------------------------------------------
// k_gram: per 128-pt chunk, MFMA Gram tile (4 quadrant waves), then contract
// the register-resident G-tile against MS into 36 logits via rotation-bucketed
// accumulators + LDS scatter + atomicAdd. No G/partials ever hit memory.
// ---------------------------------------------------------------------------
__global__ __launch_bounds__(256, 2) void k_gram(const float* __restrict__ feat,
                                                 const float* __restrict__ MS,
                                                 float* __restrict__ logits) {
    const int kc  = blockIdx.x & 63;
    const int b   = blockIdx.x >> 6;
    const int n0  = kc * 128;
    const int tid = threadIdx.x;
    const int wid = tid >> 6, lane = tid & 63;
    const int l15 = lane & 15, l4 = lane >> 4;
    const int qp = (wid >> 1) * 96, qq = (wid & 1) * 96;

    __shared__ f16 T[2][P2 * 32];        // double-buffered [row=c*3+t][nn]
    __shared__ float SRED[4][36][66];    // per-wave logit reduce

    const float* fb = feat + (size_t)b * CHN * NPTS * 3;

    f32x4 acc[6][6];
#pragma unroll
    for (int i = 0; i < 6; i++)
#pragma unroll
        for (int j = 0; j < 6; j++) acc[i][j] = (f32x4){0.f, 0.f, 0.f, 0.f};

    // stage step 0: 64 ch x 32 pts x 3 = 1536 float4 / 256 thr
#pragma unroll
    for (int i = 0; i < 6; i++) {
        int idx = tid + i * 256;
        int c = idx / 24, j = idx - (idx / 24) * 24;
        float4 v = *(const float4*)(fb + ((size_t)c * NPTS + n0) * 3 + j * 4);
        float vv[4] = {v.x, v.y, v.z, v.w};
#pragma unroll
        for (int u = 0; u < 4; u++) {
            int e = j * 4 + u, nn = e / 3, t = e - 3 * (e / 3);
            T[0][(c * 3 + t) * 32 + nn] = (f16)vv[u];
        }
    }
    __syncthreads();

    for (int ks = 0; ks < 4; ks++) {
        const int cur = ks & 1;
        float4 stg[6];
        if (ks < 3) {
#pragma unroll
            for (int i = 0; i < 6; i++) {
                int idx = tid + i * 256;
                int c = idx / 24, j = idx - (idx / 24) * 24;
                stg[i] = *(const float4*)(fb + ((size_t)c * NPTS + n0 + (ks + 1) * 32) * 3 + j * 4);
            }
        }
        f16x8 af[6], bf[6];
#pragma unroll
        for (int mt = 0; mt < 6; mt++)
            af[mt] = *(const f16x8*)&T[cur][(qp + mt * 16 + l15) * 32 + l4 * 8];
#pragma unroll
        for (int nt = 0; nt < 6; nt++)
            bf[nt] = *(const f16x8*)&T[cur][(qq + nt * 16 + l15) * 32 + l4 * 8];
#pragma unroll
        for (int mt = 0; mt < 6; mt++)
#pragma unroll
            for (int nt = 0; nt < 6; nt++)
                acc[mt][nt] = __builtin_amdgcn_mfma_f32_16x16x32_f16(af[mt], bf[nt], acc[mt][nt], 0, 0, 0);
        if (ks < 3) {
#pragma unroll
            for (int i = 0; i < 6; i++) {
                int idx = tid + i * 256;
                int c = idx / 24, j = idx - (idx / 24) * 24;
                float vv[4] = {stg[i].x, stg[i].y, stg[i].z, stg[i].w};
#pragma unroll
                for (int u = 0; u < 4; u++) {
                    int e = j * 4 + u, nn = e / 3, t = e - 3 * (e / 3);
                    T[cur ^ 1][(c * 3 + t) * 32 + nn] = (f16)vv[u];
                }
            }
        }
        __syncthreads();
    }

    // ---- logit epilogue ----
    // true t = (mt + r + l4) mod 3, true s = (nt + l15) mod 3.
    // Accumulate in rotated (compile-time) buckets l[h][(mt+r)%3 * 3 + nt%3].
    float l[36];
#pragma unroll
    for (int i = 0; i < 36; i++) l[i] = 0.0f;
    int c2v[6];
#pragma unroll
    for (int nt = 0; nt < 6; nt++) { int q = qq + nt * 16 + l15; c2v[nt] = q / 3; }
#pragma unroll
    for (int mt = 0; mt < 6; mt++) {
#pragma unroll
        for (int r = 0; r < 4; r++) {
            int p = qp + mt * 16 + l4 * 4 + r;
            int c = p / 3;
            const f32x4* msrow = (const f32x4*)(MS + (size_t)c * 256);
#pragma unroll
            for (int nt = 0; nt < 6; nt++) {
                f32x4 ms = msrow[c2v[nt]];      // 4 heads
                float g = acc[mt][nt][r];
                const int ts = ((mt + r) % 3) * 3 + (nt % 3);
                l[ts]      = fmaf(ms[0], g, l[ts]);
                l[9 + ts]  = fmaf(ms[1], g, l[9 + ts]);
                l[18 + ts] = fmaf(ms[2], g, l[18 + ts]);
                l[27 + ts] = fmaf(ms[3], g, l[27 + ts]);
            }
        }
    }
    // scatter rotated buckets to true (t,s) rows in LDS (runtime addr OK)
    const int pt = l4 % 3, ps = l15 % 3;
    int rowmap[9];
#pragma unroll
    for (int tt = 0; tt < 3; tt++)
#pragma unroll
        for (int ss = 0; ss < 3; ss++)
            rowmap[tt * 3 + ss] = ((tt + pt) % 3) * 3 + ((ss + ps) % 3);
#pragma unroll
    for (int h = 0; h < 4; h++)
#pragma unroll
        for (int i9 = 0; i9 < 9; i9++)
            SRED[wid][h * 9 + rowmap[i9]][lane] = l[h * 9 + i9];
    __syncthreads();
    if (tid < 144) {
        int w = tid / 36, row = tid - (tid / 36) * 36;
        float s = 0.0f;
#pragma unroll 8
        for (int col = 0; col < 64; col++) s += SRED[w][row][col];
        atomicAdd(&logits[b * 36 + row], s);
    }
}

// ---------------------------------------------------------------------------
// k_abig: Ab[b][p2][q2] = fp16( sum_h softmax(logits)[h][t][s] * P[h][o][c] )
//   (identity NOT folded; residual handled in k_apply)
// ---------------------------------------------------------------------------
__global__ __launch_bounds__(256) void k_abig(const float* __restrict__ logits,
                                              const float* __restrict__ P,
                                              f16* __restrict__ Ab) {
    int i = blockIdx.x * 256 + threadIdx.x;      // exactly BATCH*GG threads
    int b  = i / GG;
    int rr = i - b * GG;
    int p2 = rr / P2, q2 = rr - p2 * P2;
    int o = p2 / 3, t = p2 - 3 * (p2 / 3);
    int c = q2 / 3, s = q2 - 3 * (q2 / 3);
    const float inv = 0.07216878364870322f;      // 1/sqrt(192)
    float acc = 0.0f;
#pragma unroll
    for (int h = 0; h < 4; h++) {
        const float* lg = logits + b * 36 + h * 9 + t * 3;
        float z0 = lg[0] * inv, z1 = lg[1] * inv, z2 = lg[2] * inv;
        float mx = fmaxf(z0, fmaxf(z1, z2));
        float e0 = expf(z0 - mx), e1 = expf(z1 - mx), e2 = expf(z2 - mx);
        float zs = (s == 0) ? z0 : ((s == 1) ? z1 : z2);
        float w = expf(zs - mx) / (e0 + e1 + e2);
        acc = fmaf(w, P[h * 4096 + o * 64 + c], acc);
    }
    Ab[i] = (f16)acc;
}

// ---------------------------------------------------------------------------
// k_apply: out[b][o][n][t] = feat + sum_q2 Ab[p2][q2] * X[n][q2]
// Fused transpose-stage of feat into LDS X[32][200] fp16; MFMA; residual
// taken from X. A-fragments stream from L2.
// ---------------------------------------------------------------------------
__global__ __launch_bounds__(256, 4) void k_apply(const float* __restrict__ feat,
                                                  const f16* __restrict__ Ab,
                                                  float* __restrict__ out) {
    const int nb  = blockIdx.x & 255;
    const int b   = blockIdx.x >> 8;
    const int n0  = nb * 32;
    const int tid = threadIdx.x;
    const int wid = tid >> 6, lane = tid & 63;
    const int l15 = lane & 15, l4 = lane >> 4;

    __shared__ f16 X[32 * 200];          // [nn][q2], padded 192->200

    const float* fb = feat + (size_t)b * CHN * NPTS * 3;
    const f16* A = Ab + (size_t)b * GG;

#pragma unroll
    for (int i = 0; i < 6; i++) {
        int idx = tid + i * 256;
        int c = idx / 24, j = idx - (idx / 24) * 24;
        float4 v = *(const float4*)(fb + ((size_t)c * NPTS + n0) * 3 + j * 4);
        float vv[4] = {v.x, v.y, v.z, v.w};
#pragma unroll
        for (int u = 0; u < 4; u++) {
            int e = j * 4 + u, nn = e / 3, s = e - 3 * (e / 3);
            X[nn * 200 + c * 3 + s] = (f16)vv[u];
        }
    }
    __syncthreads();

    f32x4 acc[3][2];
#pragma unroll
    for (int i = 0; i < 3; i++)
#pragma unroll
        for (int j = 0; j < 2; j++) acc[i][j] = (f32x4){0.f, 0.f, 0.f, 0.f};

#pragma unroll
    for (int ks = 0; ks < 6; ks++) {
        f16x8 af[3], bf[2];
#pragma unroll
        for (int mt = 0; mt < 3; mt++) {
            int p2 = wid * 48 + mt * 16 + l15;
            af[mt] = *(const f16x8*)(A + (size_t)p2 * P2 + ks * 32 + l4 * 8);
        }
#pragma unroll
        for (int nt = 0; nt < 2; nt++) {
            int nl = nt * 16 + l15;
            bf[nt] = *(const f16x8*)&X[nl * 200 + ks * 32 + l4 * 8];
        }
#pragma unroll
        for (int mt = 0; mt < 3; mt++)
#pragma unroll
            for (int nt = 0; nt < 2; nt++)
                acc[mt][nt] = __builtin_amdgcn_mfma_f32_16x16x32_f16(af[mt], bf[nt], acc[mt][nt], 0, 0, 0);
    }

    float* ob = out + (size_t)b * CHN * NPTS * 3;
#pragma unroll
    for (int mt = 0; mt < 3; mt++) {
        int p2b = wid * 48 + mt * 16 + l4 * 4;
#pragma unroll
        for (int nt = 0; nt < 2; nt++) {
            int nl = nt * 16 + l15;
            f16x4 rx = *(const f16x4*)&X[nl * 200 + p2b];
#pragma unroll
            for (int r = 0; r < 4; r++) {
                int p2 = p2b + r;
                int o = p2 / 3, t = p2 - 3 * (p2 / 3);
                ob[((size_t)o * NPTS + n0 + nl) * 3 + t] = (float)rx[r] + acc[mt][nt][r];
            }
        }
    }
}

extern "C" void kernel_launch(void* const* d_in, const int* in_sizes, int n_in,
                              void* d_out, int out_size, void* d_ws, size_t ws_size,
                              hipStream_t stream) {
    const float* feat = (const float*)d_in[0];
    const float* Wq   = (const float*)d_in[2];
    const float* Wk   = (const float*)d_in[3];
    const float* Wv   = (const float*)d_in[4];
    const float* Wout = (const float*)d_in[5];
    float* out = (float*)d_out;

    char* w8 = (char*)d_ws;                    // total ws use: ~722 KB
    f16*   Ab     = (f16*)w8;                  // 589,824 B
    float* MS     = (float*)(w8 + 589824);     //  65,536 B
    float* P      = (float*)(w8 + 655360);     //  65,536 B
    float* logits = (float*)(w8 + 720896);     //   1,152 B

    k_mp   <<<8,    256, 0, stream>>>(Wq, Wk, Wv, Wout, MS, P, logits);
    k_gram <<<512,  256, 0, stream>>>(feat, MS, logits);
    k_abig <<<1152, 256, 0, stream>>>(logits, P, Ab);
    k_apply<<<2048, 256, 0, stream>>>(feat, Ab, out);
}